// Round 3
// baseline (110.294 us; speedup 1.0000x reference)
//
#include <hip/hip_runtime.h>

#define N_NEURONS 1024
#define TABLE_SIZE 65536
#define BATCH 8192
#define NGROUPS 8            // one neuron-group per XCD (block b -> XCD b%8)
#define NPG 128              // neurons (table rows) per group
#define SPB 64               // samples per block
#define TPS 4                // threads per sample (quarters)

// Pass 1: neuron-major partial sums, XCD-affine, synchronized 16-row sweep.
// Block b: group g = b&7 (XCD g), samples [(b>>3)*64, +64).
// Thread t: quarter q = t&3, sample sid = t>>2. Quarter q owns rows
// {g*128 + c*16 + q*4 + r} for chunk c=0..7, r=0..3.
// All threads in a group sweep chunks in lockstep; the v/w register
// alternation keeps at most 2 chunks (32 rows ~= 7 MB/XCD) in flight.
__global__ __launch_bounds__(256) void qw_partial_kernel(
    const int* __restrict__ data,
    const float* __restrict__ table,
    float* __restrict__ part)           // [NGROUPS][BATCH]
{
    const int b      = blockIdx.x;
    const int g      = b & (NGROUPS - 1);
    const int sub    = b >> 3;
    const int t      = threadIdx.x;
    const int q      = t & (TPS - 1);
    const int sid    = t >> 2;
    const int sample = sub * SPB + sid;

    // Index preload: 8 x int4, 64B-granular; a wave covers 16 samples'
    // contiguous 64B chunks -> every fetched line fully consumed.
    const int* __restrict__ dptr =
        data + (size_t)sample * N_NEURONS + g * NPG + q * 4;
    const int4 idx0 = *reinterpret_cast<const int4*>(dptr + 0 * 16);
    const int4 idx1 = *reinterpret_cast<const int4*>(dptr + 1 * 16);
    const int4 idx2 = *reinterpret_cast<const int4*>(dptr + 2 * 16);
    const int4 idx3 = *reinterpret_cast<const int4*>(dptr + 3 * 16);
    const int4 idx4 = *reinterpret_cast<const int4*>(dptr + 4 * 16);
    const int4 idx5 = *reinterpret_cast<const int4*>(dptr + 5 * 16);
    const int4 idx6 = *reinterpret_cast<const int4*>(dptr + 6 * 16);
    const int4 idx7 = *reinterpret_cast<const int4*>(dptr + 7 * 16);

    const float* __restrict__ tb =
        table + (size_t)(g * NPG + q * 4) * TABLE_SIZE;

#define LOADC(a0, a1, a2, a3, I, c)                                   \
    a0 = tb[(size_t)((c) * 16 + 0) * TABLE_SIZE + (size_t)(I).x];     \
    a1 = tb[(size_t)((c) * 16 + 1) * TABLE_SIZE + (size_t)(I).y];     \
    a2 = tb[(size_t)((c) * 16 + 2) * TABLE_SIZE + (size_t)(I).z];     \
    a3 = tb[(size_t)((c) * 16 + 3) * TABLE_SIZE + (size_t)(I).w];

    float v0, v1, v2, v3, w0, w1, w2, w3;
    float acc = 0.0f;

    LOADC(v0, v1, v2, v3, idx0, 0);
    LOADC(w0, w1, w2, w3, idx1, 1);  acc += (v0 + v1) + (v2 + v3);
    LOADC(v0, v1, v2, v3, idx2, 2);  acc += (w0 + w1) + (w2 + w3);
    LOADC(w0, w1, w2, w3, idx3, 3);  acc += (v0 + v1) + (v2 + v3);
    LOADC(v0, v1, v2, v3, idx4, 4);  acc += (w0 + w1) + (w2 + w3);
    LOADC(w0, w1, w2, w3, idx5, 5);  acc += (v0 + v1) + (v2 + v3);
    LOADC(v0, v1, v2, v3, idx6, 6);  acc += (w0 + w1) + (w2 + w3);
    LOADC(w0, w1, w2, w3, idx7, 7);  acc += (v0 + v1) + (v2 + v3);
    acc += (w0 + w1) + (w2 + w3);
#undef LOADC

    // combine the 4 quarters of each sample (adjacent lanes)
    acc += __shfl_xor(acc, 1, 64);
    acc += __shfl_xor(acc, 2, 64);

    if (q == 0) {
        part[(size_t)g * BATCH + sample] = acc;
    }
}

// Pass 2: out[i] = sum_g part[g][i]
__global__ __launch_bounds__(256) void qw_reduce_kernel(
    const float* __restrict__ part,
    float* __restrict__ out)
{
    const int i = blockIdx.x * 256 + threadIdx.x;
    float s = 0.0f;
#pragma unroll
    for (int g = 0; g < NGROUPS; ++g) {
        s += part[(size_t)g * BATCH + i];
    }
    out[i] = s;
}

// Fallback in case d_ws is too small for partials.
__global__ __launch_bounds__(256) void qw_gather_kernel(
    const int* __restrict__ data,
    const float* __restrict__ table,
    float* __restrict__ out)
{
    const int gtid   = blockIdx.x * blockDim.x + threadIdx.x;
    const int sample = gtid >> 6;
    const int lane   = threadIdx.x & 63;
    if (sample >= BATCH) return;
    const int* __restrict__ row = data + (size_t)sample * N_NEURONS;
    float acc = 0.0f;
#pragma unroll
    for (int k = 0; k < 4; ++k) {
        const int jb = 256 * k + 4 * lane;
        const int4 idx4 = *reinterpret_cast<const int4*>(row + jb);
        acc += table[(size_t)(jb + 0) * TABLE_SIZE + idx4.x];
        acc += table[(size_t)(jb + 1) * TABLE_SIZE + idx4.y];
        acc += table[(size_t)(jb + 2) * TABLE_SIZE + idx4.z];
        acc += table[(size_t)(jb + 3) * TABLE_SIZE + idx4.w];
    }
#pragma unroll
    for (int off = 32; off >= 1; off >>= 1) acc += __shfl_xor(acc, off, 64);
    if (lane == 0) out[sample] = acc;
}

extern "C" void kernel_launch(void* const* d_in, const int* in_sizes, int n_in,
                              void* d_out, int out_size, void* d_ws, size_t ws_size,
                              hipStream_t stream)
{
    const int*   data  = (const int*)d_in[0];    // [BATCH, N_NEURONS] int32
    const float* table = (const float*)d_in[1];  // [N_NEURONS, TABLE_SIZE] float32
    float*       out   = (float*)d_out;          // [BATCH] float32

    const size_t need = (size_t)NGROUPS * BATCH * sizeof(float);  // 256 KB
    if (ws_size >= need) {
        float* part = (float*)d_ws;
        const int blocks = (BATCH / SPB) * NGROUPS;  // 1024 = 4 blocks/CU
        qw_partial_kernel<<<blocks, 256, 0, stream>>>(data, table, part);
        qw_reduce_kernel<<<BATCH / 256, 256, 0, stream>>>(part, out);
    } else {
        qw_gather_kernel<<<BATCH / 4, 256, 0, stream>>>(data, table, out);
    }
}

// Round 5
// 85.745 us; speedup vs baseline: 1.2863x; 1.2863x over previous
//
#include <hip/hip_runtime.h>

#define N_NEURONS 1024
#define TABLE_SIZE 65536
#define BATCH 8192
#define NGROUPS 8            // one neuron-group per XCD (block b -> XCD b%8)
#define NPG 128              // neurons (table rows) per group
#define SPB 128              // samples per block
#define NCHUNK 8             // 8 chunks x 16-row window = 128 rows  (FIXED)

// Pass 1: neuron-major partial sums, XCD-affine, barrier-paced 16-row window.
// Block b: group g = b&7 (XCD g), samples [(b>>3)*128, +128).
// Thread t: half h = t&1, sample sid = t>>1.
// Chunk c: the WHOLE BLOCK gathers only rows [g*128 + c*16, +16);
// half h owns rows c*16 + h*8 + (0..7)  -> 8 independent gathers per thread
// per chunk; __syncthreads() between chunks keeps the ~3.6 MB window
// resident in the XCD's 4 MiB L2.
__global__ __launch_bounds__(256) void qw_partial_kernel(
    const int* __restrict__ data,
    const float* __restrict__ table,
    float* __restrict__ part)           // [NGROUPS][BATCH]
{
    const int b      = blockIdx.x;
    const int g      = b & (NGROUPS - 1);
    const int sub    = b >> 3;
    const int t      = threadIdx.x;
    const int h      = t & 1;
    const int sid    = t >> 1;                       // 0..127
    const int sample = sub * SPB + sid;

    // Chunk c's 8 indices for this thread live at dptr + c*16 (rows
    // g*128 + c*16 + h*8 + 0..7). Lane pairs read adjacent 32-B halves.
    const int* __restrict__ dptr =
        data + (size_t)sample * N_NEURONS + g * NPG + h * 8;

    // Table base folded with the half offset; chunk c adds c*16 rows.
    const float* __restrict__ tb =
        table + (size_t)(g * NPG + h * 8) * TABLE_SIZE;

    // software-pipelined idx regs (chunk c+1 prefetched during chunk c)
    int4 i0 = *reinterpret_cast<const int4*>(dptr);
    int4 i1 = *reinterpret_cast<const int4*>(dptr + 4);

    float acc = 0.0f;
#pragma unroll
    for (int c = 0; c < NCHUNK; ++c) {
        const int4 c0 = i0;
        const int4 c1 = i1;
        if (c + 1 < NCHUNK) {
            const int* __restrict__ p = dptr + (c + 1) * 16;
            i0 = *reinterpret_cast<const int4*>(p);
            i1 = *reinterpret_cast<const int4*>(p + 4);
        }
        const float* __restrict__ tc = tb + (size_t)(c * 16) * TABLE_SIZE;
        // 8 independent gathers, all within the block's current 16-row window
        const float v0 = tc[(size_t)0 * TABLE_SIZE + (size_t)c0.x];
        const float v1 = tc[(size_t)1 * TABLE_SIZE + (size_t)c0.y];
        const float v2 = tc[(size_t)2 * TABLE_SIZE + (size_t)c0.z];
        const float v3 = tc[(size_t)3 * TABLE_SIZE + (size_t)c0.w];
        const float v4 = tc[(size_t)4 * TABLE_SIZE + (size_t)c1.x];
        const float v5 = tc[(size_t)5 * TABLE_SIZE + (size_t)c1.y];
        const float v6 = tc[(size_t)6 * TABLE_SIZE + (size_t)c1.z];
        const float v7 = tc[(size_t)7 * TABLE_SIZE + (size_t)c1.w];
        acc += ((v0 + v1) + (v2 + v3)) + ((v4 + v5) + (v6 + v7));
        __syncthreads();   // pace all 4 waves of the block to the same window
    }

    // combine the two halves of each sample (adjacent lanes)
    acc += __shfl_xor(acc, 1, 64);
    if (h == 0) {
        part[(size_t)g * BATCH + sample] = acc;
    }
}

// Pass 2: out[i] = sum_g part[g][i]
__global__ __launch_bounds__(256) void qw_reduce_kernel(
    const float* __restrict__ part,
    float* __restrict__ out)
{
    const int i = blockIdx.x * 256 + threadIdx.x;
    float s = 0.0f;
#pragma unroll
    for (int g = 0; g < NGROUPS; ++g) {
        s += part[(size_t)g * BATCH + i];
    }
    out[i] = s;
}

// Fallback in case d_ws is too small for partials.
__global__ __launch_bounds__(256) void qw_gather_kernel(
    const int* __restrict__ data,
    const float* __restrict__ table,
    float* __restrict__ out)
{
    const int gtid   = blockIdx.x * blockDim.x + threadIdx.x;
    const int sample = gtid >> 6;
    const int lane   = threadIdx.x & 63;
    if (sample >= BATCH) return;
    const int* __restrict__ row = data + (size_t)sample * N_NEURONS;
    float acc = 0.0f;
#pragma unroll
    for (int k = 0; k < 4; ++k) {
        const int jb = 256 * k + 4 * lane;
        const int4 idx4 = *reinterpret_cast<const int4*>(row + jb);
        acc += table[(size_t)(jb + 0) * TABLE_SIZE + idx4.x];
        acc += table[(size_t)(jb + 1) * TABLE_SIZE + idx4.y];
        acc += table[(size_t)(jb + 2) * TABLE_SIZE + idx4.z];
        acc += table[(size_t)(jb + 3) * TABLE_SIZE + idx4.w];
    }
#pragma unroll
    for (int off = 32; off >= 1; off >>= 1) acc += __shfl_xor(acc, off, 64);
    if (lane == 0) out[sample] = acc;
}

extern "C" void kernel_launch(void* const* d_in, const int* in_sizes, int n_in,
                              void* d_out, int out_size, void* d_ws, size_t ws_size,
                              hipStream_t stream)
{
    const int*   data  = (const int*)d_in[0];    // [BATCH, N_NEURONS] int32
    const float* table = (const float*)d_in[1];  // [N_NEURONS, TABLE_SIZE] float32
    float*       out   = (float*)d_out;          // [BATCH] float32

    const size_t need = (size_t)NGROUPS * BATCH * sizeof(float);  // 256 KB
    if (ws_size >= need) {
        float* part = (float*)d_ws;
        const int blocks = (BATCH / SPB) * NGROUPS;  // 512 = 2 blocks/CU
        qw_partial_kernel<<<blocks, 256, 0, stream>>>(data, table, part);
        qw_reduce_kernel<<<BATCH / 256, 256, 0, stream>>>(part, out);
    } else {
        qw_gather_kernel<<<BATCH / 4, 256, 0, stream>>>(data, table, out);
    }
}

// Round 6
// 84.169 us; speedup vs baseline: 1.3104x; 1.0187x over previous
//
#include <hip/hip_runtime.h>

#define N_NEURONS 1024
#define TABLE_SIZE 65536
#define BATCH 8192
#define NGROUPS 8            // one neuron-group per XCD (block b -> XCD b%8)
#define NPG 128              // neurons (table rows) per group
#define SPB 128              // samples per block
#define NCHUNK 8             // 8 chunks x 16-row window = 128 rows
#define TS ((size_t)TABLE_SIZE)

// Pass 1: neuron-major partial sums, XCD-affine, RAW-barrier-paced 16-row
// window with register double-buffered gathers.
// Block b: group g = b&7 (XCD g), samples [(b>>3)*128, +128).
// Thread t: half h = t&1, sample sid = t>>1.
// Chunk c: rows [g*128 + c*16, +16); half h owns rows c*16 + h*8 + 0..7.
// Pipeline per epoch: issue chunk c+1's 8 gathers + prefetch chunk c+2 idx,
// raw s_barrier (NO vmcnt drain, unlike __syncthreads), then consume chunk c
// (compiler waits only on the 8 oldest loads; next chunk stays in flight).
__global__ __launch_bounds__(256) void qw_partial_kernel(
    const int* __restrict__ data,
    const float* __restrict__ table,
    float* __restrict__ part)           // [NGROUPS][BATCH]
{
    const int b      = blockIdx.x;
    const int g      = b & (NGROUPS - 1);
    const int sub    = b >> 3;
    const int t      = threadIdx.x;
    const int h      = t & 1;
    const int sid    = t >> 1;                       // 0..127
    const int sample = sub * SPB + sid;

    const int* __restrict__ dptr =
        data + (size_t)sample * N_NEURONS + g * NPG + h * 8;
    const float* __restrict__ tb =
        table + (size_t)(g * NPG + h * 8) * TABLE_SIZE;

#define IDX(c)  (*reinterpret_cast<const int4*>(dptr + (c) * 16))
#define IDX2(c) (*reinterpret_cast<const int4*>(dptr + (c) * 16 + 4))

#define GATHER(d0,d1,d2,d3,d4,d5,d6,d7, c, I0, I1)                    \
    d0 = tb[((size_t)(c) * 16 + 0) * TS + (size_t)(I0).x];            \
    d1 = tb[((size_t)(c) * 16 + 1) * TS + (size_t)(I0).y];            \
    d2 = tb[((size_t)(c) * 16 + 2) * TS + (size_t)(I0).z];            \
    d3 = tb[((size_t)(c) * 16 + 3) * TS + (size_t)(I0).w];            \
    d4 = tb[((size_t)(c) * 16 + 4) * TS + (size_t)(I1).x];            \
    d5 = tb[((size_t)(c) * 16 + 5) * TS + (size_t)(I1).y];            \
    d6 = tb[((size_t)(c) * 16 + 6) * TS + (size_t)(I1).z];            \
    d7 = tb[((size_t)(c) * 16 + 7) * TS + (size_t)(I1).w];

#define SUM8(d0,d1,d2,d3,d4,d5,d6,d7) \
    (((d0 + d1) + (d2 + d3)) + ((d4 + d5) + (d6 + d7)))

    // idx regs: p = even chunks' feed, q = odd chunks' feed (2 ahead)
    int4 p0 = IDX(0), p1 = IDX2(0);
    int4 q0 = IDX(1), q1 = IDX2(1);

    float A0,A1,A2,A3,A4,A5,A6,A7;
    float B0,B1,B2,B3,B4,B5,B6,B7;
    float acc = 0.0f;

    // prologue: chunk 0 gathers in flight
    GATHER(A0,A1,A2,A3,A4,A5,A6,A7, 0, p0, p1);

    // epoch 0: issue chunk1, prefetch idx2, pace, consume chunk0
    GATHER(B0,B1,B2,B3,B4,B5,B6,B7, 1, q0, q1);
    p0 = IDX(2); p1 = IDX2(2);
    __builtin_amdgcn_s_barrier();
    acc += SUM8(A0,A1,A2,A3,A4,A5,A6,A7);

    // epoch 1: issue chunk2, prefetch idx3, pace, consume chunk1
    GATHER(A0,A1,A2,A3,A4,A5,A6,A7, 2, p0, p1);
    q0 = IDX(3); q1 = IDX2(3);
    __builtin_amdgcn_s_barrier();
    acc += SUM8(B0,B1,B2,B3,B4,B5,B6,B7);

    // epoch 2: issue chunk3, prefetch idx4, pace, consume chunk2
    GATHER(B0,B1,B2,B3,B4,B5,B6,B7, 3, q0, q1);
    p0 = IDX(4); p1 = IDX2(4);
    __builtin_amdgcn_s_barrier();
    acc += SUM8(A0,A1,A2,A3,A4,A5,A6,A7);

    // epoch 3: issue chunk4, prefetch idx5, pace, consume chunk3
    GATHER(A0,A1,A2,A3,A4,A5,A6,A7, 4, p0, p1);
    q0 = IDX(5); q1 = IDX2(5);
    __builtin_amdgcn_s_barrier();
    acc += SUM8(B0,B1,B2,B3,B4,B5,B6,B7);

    // epoch 4: issue chunk5, prefetch idx6, pace, consume chunk4
    GATHER(B0,B1,B2,B3,B4,B5,B6,B7, 5, q0, q1);
    p0 = IDX(6); p1 = IDX2(6);
    __builtin_amdgcn_s_barrier();
    acc += SUM8(A0,A1,A2,A3,A4,A5,A6,A7);

    // epoch 5: issue chunk6, prefetch idx7, pace, consume chunk5
    GATHER(A0,A1,A2,A3,A4,A5,A6,A7, 6, p0, p1);
    q0 = IDX(7); q1 = IDX2(7);
    __builtin_amdgcn_s_barrier();
    acc += SUM8(B0,B1,B2,B3,B4,B5,B6,B7);

    // epoch 6: issue chunk7, pace, consume chunk6
    GATHER(B0,B1,B2,B3,B4,B5,B6,B7, 7, q0, q1);
    __builtin_amdgcn_s_barrier();
    acc += SUM8(A0,A1,A2,A3,A4,A5,A6,A7);

    // epoch 7: consume chunk7
    acc += SUM8(B0,B1,B2,B3,B4,B5,B6,B7);

#undef GATHER
#undef SUM8
#undef IDX
#undef IDX2

    // combine the two halves of each sample (adjacent lanes)
    acc += __shfl_xor(acc, 1, 64);
    if (h == 0) {
        part[(size_t)g * BATCH + sample] = acc;
    }
}

// Pass 2: out[i] = sum_g part[g][i]
__global__ __launch_bounds__(256) void qw_reduce_kernel(
    const float* __restrict__ part,
    float* __restrict__ out)
{
    const int i = blockIdx.x * 256 + threadIdx.x;
    float s = 0.0f;
#pragma unroll
    for (int g = 0; g < NGROUPS; ++g) {
        s += part[(size_t)g * BATCH + i];
    }
    out[i] = s;
}

// Fallback in case d_ws is too small for partials.
__global__ __launch_bounds__(256) void qw_gather_kernel(
    const int* __restrict__ data,
    const float* __restrict__ table,
    float* __restrict__ out)
{
    const int gtid   = blockIdx.x * blockDim.x + threadIdx.x;
    const int sample = gtid >> 6;
    const int lane   = threadIdx.x & 63;
    if (sample >= BATCH) return;
    const int* __restrict__ row = data + (size_t)sample * N_NEURONS;
    float acc = 0.0f;
#pragma unroll
    for (int k = 0; k < 4; ++k) {
        const int jb = 256 * k + 4 * lane;
        const int4 idx4 = *reinterpret_cast<const int4*>(row + jb);
        acc += table[(size_t)(jb + 0) * TABLE_SIZE + idx4.x];
        acc += table[(size_t)(jb + 1) * TABLE_SIZE + idx4.y];
        acc += table[(size_t)(jb + 2) * TABLE_SIZE + idx4.z];
        acc += table[(size_t)(jb + 3) * TABLE_SIZE + idx4.w];
    }
#pragma unroll
    for (int off = 32; off >= 1; off >>= 1) acc += __shfl_xor(acc, off, 64);
    if (lane == 0) out[sample] = acc;
}

extern "C" void kernel_launch(void* const* d_in, const int* in_sizes, int n_in,
                              void* d_out, int out_size, void* d_ws, size_t ws_size,
                              hipStream_t stream)
{
    const int*   data  = (const int*)d_in[0];    // [BATCH, N_NEURONS] int32
    const float* table = (const float*)d_in[1];  // [N_NEURONS, TABLE_SIZE] float32
    float*       out   = (float*)d_out;          // [BATCH] float32

    const size_t need = (size_t)NGROUPS * BATCH * sizeof(float);  // 256 KB
    if (ws_size >= need) {
        float* part = (float*)d_ws;
        const int blocks = (BATCH / SPB) * NGROUPS;  // 512 = 2 blocks/CU
        qw_partial_kernel<<<blocks, 256, 0, stream>>>(data, table, part);
        qw_reduce_kernel<<<BATCH / 256, 256, 0, stream>>>(part, out);
    } else {
        qw_gather_kernel<<<BATCH / 4, 256, 0, stream>>>(data, table, out);
    }
}